// Round 7
// baseline (802.585 us; speedup 1.0000x reference)
//
#include <hip/hip_runtime.h>

#define B_SZ 8
#define L_SZ 4096
#define H_SZ 512
#define P_SZ 512
#define M_SZ (B_SZ * L_SZ)      // 32768
#define NCH 32
#define CHUNK (L_SZ / NCH)      // 128
#define PH (P_SZ * H_SZ)
#define MP ((size_t)M_SZ * P_SZ)

typedef __attribute__((ext_vector_type(8))) __bf16 bf16x8;
typedef __attribute__((ext_vector_type(4))) float f32x4;

// RNE fp32 -> bf16 split: x ~= hi + lo, each bf16.
__device__ __forceinline__ void splitf(float x, unsigned short& h, unsigned short& l) {
    unsigned u = __float_as_uint(x);
    unsigned hr = (u + 0x7fffu + ((u >> 16) & 1u)) >> 16;
    h = (unsigned short)hr;
    float lo = x - __uint_as_float(hr << 16);       // exact (Sterbenz)
    unsigned ul = __float_as_uint(lo);
    l = (unsigned short)((ul + 0x7fffu + ((ul >> 16) & 1u)) >> 16);
}

__device__ __forceinline__ float b2f(unsigned short u) {
    return __uint_as_float((unsigned)u << 16);
}

__global__ void precompute_k(const float* __restrict__ lam_re,
                             const float* __restrict__ lam_im,
                             const float* __restrict__ log_step,
                             float2* __restrict__ Lbar,
                             float2* __restrict__ AS,
                             float2* __restrict__ scale) {
    int p = blockIdx.x * blockDim.x + threadIdx.x;
    if (p >= P_SZ) return;
    float lr = lam_re[p], li = lam_im[p];
    float dt = expf(log_step[p]);
    float zr = lr * dt, zi = li * dt;
    float er = expf(zr);
    float ar = er * cosf(zi), ai = er * sinf(zi);
    Lbar[p] = make_float2(ar, ai);
    float nr = ar - 1.0f, ni = ai;
    float d2 = lr * lr + li * li;
    scale[p] = make_float2((nr * lr + ni * li) / d2, (ni * lr - nr * li) / d2);
    float xr = ar, xi = ai;
    #pragma unroll
    for (int i = 0; i < 7; i++) {      // A^128 via squarings
        float tr = xr * xr - xi * xi;
        float ti = 2.0f * xr * xi;
        xr = tr; xi = ti;
    }
    AS[p] = make_float2(xr, xi);
}

// Ppow[t][p] = Lbar[p]^(t+1)  (carry-correction coefficients; 512 KB, L2-hot)
__global__ void ppow_k(const float2* __restrict__ Lbar,
                       float2* __restrict__ Ppow) {
    int idx = blockIdx.x * blockDim.x + threadIdx.x;
    if (idx >= CHUNK * P_SZ) return;
    int p = idx & (P_SZ - 1);
    int t = idx >> 9;
    int e = t + 1;
    float2 base = Lbar[p];
    float rr = 1.0f, ri = 0.0f;
    float br = base.x, bi = base.y;
    #pragma unroll
    for (int bit = 0; bit < 8; bit++) {
        if ((e >> bit) & 1) {
            float nr = rr * br - ri * bi;
            float ni = rr * bi + ri * br;
            rr = nr; ri = ni;
        }
        float sr = br * br - bi * bi;
        float si = 2.0f * br * bi;
        br = sr; bi = si;
    }
    Ppow[idx] = make_float2(rr, ri);
}

__global__ void bbar_k(const float* __restrict__ Bre,
                       const float* __restrict__ Bim,
                       const float2* __restrict__ scale,
                       unsigned short* __restrict__ Wpl) {
    int idx = blockIdx.x * blockDim.x + threadIdx.x;
    if (idx >= PH) return;
    int p = idx / H_SZ;
    float2 s = scale[p];
    float br = Bre[idx], bi = Bim[idx];
    float wr = s.x * br - s.y * bi;
    float wi = s.x * bi + s.y * br;
    unsigned short h, l;
    splitf(wr, h, l);
    Wpl[idx] = h; Wpl[PH + idx] = l;
    splitf(wi, h, l);
    Wpl[2 * PH + idx] = h; Wpl[3 * PH + idx] = l;
}

__global__ void csplit_k(const float* __restrict__ Cre,
                         const float* __restrict__ Cim,
                         unsigned short* __restrict__ Cpl) {
    int idx = blockIdx.x * blockDim.x + threadIdx.x;
    if (idx >= PH) return;
    unsigned short h, l;
    splitf(Cre[idx], h, l);
    Cpl[idx] = h; Cpl[PH + idx] = l;
    splitf(-Cim[idx], h, l);
    Cpl[2 * PH + idx] = h; Cpl[3 * PH + idx] = l;
}

__device__ __forceinline__ void deswizzle(int bid, int& m, int& n) {
    int xcd = bid & 7;
    n = (bid >> 3) & 7;
    m = ((bid >> 6) << 3) + xcd;
}

// GEMM1 + fused local chunk scan (R5-proven structure). Writes x_local as
// 4 bf16 planes and chunk summaries to carries.
__global__ __launch_bounds__(256) void gemm1_k(const float* __restrict__ U,
                                               const unsigned short* __restrict__ Wpl,
                                               const float2* __restrict__ Lbar,
                                               unsigned short* __restrict__ Xpl,
                                               float2* __restrict__ carries) {
    __shared__ __align__(16) char smem[65536];
    unsigned short* sUh = (unsigned short*)smem;        // 8KB
    unsigned short* sUl = sUh + 128 * 32;               // 8KB
    unsigned short* sW  = sUl + 128 * 32;               // 16KB
    const int tid = threadIdx.x;
    int g, nb;
    deswizzle(blockIdx.x, g, nb);
    const int m0 = g * 128;
    const int n0 = nb * 64;
    const int lane = tid & 63, wvv = tid >> 6;
    const int wm = wvv & 1, wn = wvv >> 1;
    const int lr = lane & 15, kg = lane >> 4;

    f32x4 accr[4][2], acci[4][2];
    #pragma unroll
    for (int i = 0; i < 4; i++)
        #pragma unroll
        for (int j = 0; j < 2; j++) { accr[i][j] = (f32x4)0.0f; acci[i][j] = (f32x4)0.0f; }

    const int urow = tid >> 3, uc4 = tid & 7;
    const int wrow = tid >> 2, wc8 = tid & 3;

    float4 ust[4];
    int4 wst[4];
    #pragma unroll
    for (int q = 0; q < 4; q++)
        ust[q] = *(const float4*)&U[(size_t)(m0 + urow + q * 32) * H_SZ + uc4 * 4];
    #pragma unroll
    for (int q = 0; q < 4; q++)
        wst[q] = *(const int4*)&Wpl[(size_t)q * PH + (size_t)(n0 + wrow) * H_SZ + wc8 * 8];

    for (int k0 = 0; k0 < H_SZ; k0 += 32) {
        __syncthreads();                       // prev iter's LDS reads done
        #pragma unroll
        for (int q = 0; q < 4; q++) {
            int row = urow + q * 32;
            ushort4 hv, lv;
            splitf(ust[q].x, hv.x, lv.x);
            splitf(ust[q].y, hv.y, lv.y);
            splitf(ust[q].z, hv.z, lv.z);
            splitf(ust[q].w, hv.w, lv.w);
            *(ushort4*)&sUh[row * 32 + uc4 * 4] = hv;
            *(ushort4*)&sUl[row * 32 + uc4 * 4] = lv;
        }
        #pragma unroll
        for (int q = 0; q < 4; q++)
            *(int4*)&sW[q * 2048 + wrow * 32 + wc8 * 8] = wst[q];
        __syncthreads();
        if (k0 + 32 < H_SZ) {
            #pragma unroll
            for (int q = 0; q < 4; q++)
                ust[q] = *(const float4*)&U[(size_t)(m0 + urow + q * 32) * H_SZ + k0 + 32 + uc4 * 4];
            #pragma unroll
            for (int q = 0; q < 4; q++)
                wst[q] = *(const int4*)&Wpl[(size_t)q * PH + (size_t)(n0 + wrow) * H_SZ + k0 + 32 + wc8 * 8];
        }

        bf16x8 uh[4], ul[4];
        #pragma unroll
        for (int mi = 0; mi < 4; mi++) {
            int off = (wm * 64 + mi * 16 + lr) * 32 + kg * 8;
            uh[mi] = *(const bf16x8*)&sUh[off];
            ul[mi] = *(const bf16x8*)&sUl[off];
        }
        bf16x8 wrh[2], wrl[2], wih[2], wil[2];
        #pragma unroll
        for (int nj = 0; nj < 2; nj++) {
            int off = (wn * 32 + nj * 16 + lr) * 32 + kg * 8;
            wrh[nj] = *(const bf16x8*)&sW[0 * 2048 + off];
            wrl[nj] = *(const bf16x8*)&sW[1 * 2048 + off];
            wih[nj] = *(const bf16x8*)&sW[2 * 2048 + off];
            wil[nj] = *(const bf16x8*)&sW[3 * 2048 + off];
        }
        #pragma unroll
        for (int mi = 0; mi < 4; mi++)
            #pragma unroll
            for (int nj = 0; nj < 2; nj++) {
                accr[mi][nj] = __builtin_amdgcn_mfma_f32_16x16x32_bf16(uh[mi], wrh[nj], accr[mi][nj], 0, 0, 0);
                accr[mi][nj] = __builtin_amdgcn_mfma_f32_16x16x32_bf16(uh[mi], wrl[nj], accr[mi][nj], 0, 0, 0);
                accr[mi][nj] = __builtin_amdgcn_mfma_f32_16x16x32_bf16(ul[mi], wrh[nj], accr[mi][nj], 0, 0, 0);
                acci[mi][nj] = __builtin_amdgcn_mfma_f32_16x16x32_bf16(uh[mi], wih[nj], acci[mi][nj], 0, 0, 0);
                acci[mi][nj] = __builtin_amdgcn_mfma_f32_16x16x32_bf16(uh[mi], wil[nj], acci[mi][nj], 0, 0, 0);
                acci[mi][nj] = __builtin_amdgcn_mfma_f32_16x16x32_bf16(ul[mi], wih[nj], acci[mi][nj], 0, 0, 0);
            }
    }

    // ---- epilogue: local chunk scan in LDS (R5-proven, stride-64) ----
    __syncthreads();
    float2* xs = (float2*)smem;                // [128 t][64 p] = 64KB
    #pragma unroll
    for (int mi = 0; mi < 4; mi++)
        #pragma unroll
        for (int nj = 0; nj < 2; nj++)
            #pragma unroll
            for (int r = 0; r < 4; r++) {
                int t = wm * 64 + mi * 16 + kg * 4 + r;
                int p = wn * 32 + nj * 16 + lr;
                xs[t * 64 + p] = make_float2(accr[mi][nj][r], acci[mi][nj][r]);
            }
    __syncthreads();
    if (tid < 64) {
        float2 A = Lbar[n0 + tid];
        float xr = 0.f, xi = 0.f;
        for (int t = 0; t < CHUNK; t++) {
            float2 v = xs[t * 64 + tid];
            float nr = fmaf(A.x, xr, fmaf(-A.y, xi, v.x));
            float ni = fmaf(A.x, xi, fmaf(A.y, xr, v.y));
            xr = nr; xi = ni;
            xs[t * 64 + tid] = make_float2(xr, xi);
        }
        carries[(size_t)g * P_SZ + n0 + tid] = make_float2(xr, xi);
    }
    __syncthreads();
    const float4* xs4 = (const float4*)xs;
    #pragma unroll
    for (int it = 0; it < 16; it++) {
        int lin = tid + it * 256;
        int row = lin >> 5;                    // 0..127
        int c4  = lin & 31;                    // 0..31 (pairs of complex)
        float4 v = xs4[lin];                   // 16B-aligned
        ushort2 rh, rl, ih, il;
        splitf(v.x, rh.x, rl.x);
        splitf(v.y, ih.x, il.x);
        splitf(v.z, rh.y, rl.y);
        splitf(v.w, ih.y, il.y);
        size_t base = (size_t)(m0 + row) * P_SZ + n0 + c4 * 2;
        *(ushort2*)&Xpl[0 * MP + base] = rh;
        *(ushort2*)&Xpl[1 * MP + base] = rl;
        *(ushort2*)&Xpl[2 * MP + base] = ih;
        *(ushort2*)&Xpl[3 * MP + base] = il;
    }
}

__global__ void scanB_k(float2* __restrict__ carries,
                        const float2* __restrict__ AS) {
    int tid = blockIdx.x * blockDim.x + threadIdx.x;
    int p = tid & (P_SZ - 1);
    int b = tid / P_SZ;
    float2 A = AS[p];
    float cr = 0.f, ci = 0.f;
    for (int c = 0; c < NCH; c++) {
        int idx = (b * NCH + c) * P_SZ + p;
        float2 t = carries[idx];
        carries[idx] = make_float2(cr, ci);
        float nr = fmaf(A.x, cr, fmaf(-A.y, ci, t.x));
        float ni = fmaf(A.x, ci, fmaf(A.y, cr, t.y));
        cr = nr; ci = ni;
    }
}

// In-place carry fixup on the bf16 planes: x = (hi+lo) + Lbar^(t+1)*carry
__global__ void fixup_k(unsigned short* __restrict__ Xpl,
                        const float2* __restrict__ Ppow,
                        const float2* __restrict__ carries) {
    int idx = blockIdx.x * blockDim.x + threadIdx.x;   // over M*P/4
    int m = idx >> 7;
    int p0 = (idx & 127) * 4;
    int t = m & (CHUNK - 1), g = m >> 7;
    size_t base = (size_t)m * P_SZ + p0;
    ushort4 rh = *(ushort4*)&Xpl[0 * MP + base];
    ushort4 rl = *(ushort4*)&Xpl[1 * MP + base];
    ushort4 ih = *(ushort4*)&Xpl[2 * MP + base];
    ushort4 il = *(ushort4*)&Xpl[3 * MP + base];
    float2 pw[4], cv[4];
    *(float4*)&pw[0] = *(const float4*)&Ppow[t * P_SZ + p0];
    *(float4*)&pw[2] = *(const float4*)&Ppow[t * P_SZ + p0 + 2];
    *(float4*)&cv[0] = *(const float4*)&carries[(size_t)g * P_SZ + p0];
    *(float4*)&cv[2] = *(const float4*)&carries[(size_t)g * P_SZ + p0 + 2];
    unsigned short h[4], lth[4], ihh[4], ilh[4];
    #pragma unroll
    for (int e = 0; e < 4; e++) {
        unsigned short rhe = (&rh.x)[e], rle = (&rl.x)[e];
        unsigned short ihe = (&ih.x)[e], ile = (&il.x)[e];
        float xr = b2f(rhe) + b2f(rle);
        float xi = b2f(ihe) + b2f(ile);
        xr = fmaf(pw[e].x, cv[e].x, fmaf(-pw[e].y, cv[e].y, xr));
        xi = fmaf(pw[e].x, cv[e].y, fmaf(pw[e].y, cv[e].x, xi));
        splitf(xr, h[e], lth[e]);
        splitf(xi, ihh[e], ilh[e]);
    }
    *(ushort4*)&Xpl[0 * MP + base] = make_ushort4(h[0], h[1], h[2], h[3]);
    *(ushort4*)&Xpl[1 * MP + base] = make_ushort4(lth[0], lth[1], lth[2], lth[3]);
    *(ushort4*)&Xpl[2 * MP + base] = make_ushort4(ihh[0], ihh[1], ihh[2], ihh[3]);
    *(ushort4*)&Xpl[3 * MP + base] = make_ushort4(ilh[0], ilh[1], ilh[2], ilh[3]);
}

// GEMM2: pure bf16 MFMA on pre-split planes; register-staged (R5-proven
// double-barrier + prefetch), zero split VALU in the k-loop.
__global__ __launch_bounds__(256) void gemm2_k(const unsigned short* __restrict__ Xpl,
                                               const unsigned short* __restrict__ Cpl,
                                               float* __restrict__ Y) {
    __shared__ __align__(16) unsigned short sS[24576];   // 48 KB
    const int tid = threadIdx.x;
    int g, nb;
    deswizzle(blockIdx.x, g, nb);
    const int m0 = g * 128;
    const int n0 = nb * 64;
    const int lane = tid & 63, wvv = tid >> 6;
    const int wm = wvv & 1, wn = wvv >> 1;
    const int lr = lane & 15, kg = lane >> 4;

    f32x4 acc[4][2];
    #pragma unroll
    for (int i = 0; i < 4; i++)
        #pragma unroll
        for (int j = 0; j < 2; j++) acc[i][j] = (f32x4)0.0f;

    // X: 2048 int4 (4 planes x 128 rows x 4 int4); C: 1024 int4 (4 x 64 x 4)
    int xq[8], xr_[8], xc[8], cq[4], cr_[4], cc[4];
    #pragma unroll
    for (int it = 0; it < 8; it++) {
        int lin = tid + it * 256;
        xq[it] = lin >> 9; xr_[it] = (lin & 511) >> 2; xc[it] = lin & 3;
    }
    #pragma unroll
    for (int it = 0; it < 4; it++) {
        int lin = tid + it * 256;
        cq[it] = lin >> 8; cr_[it] = (lin & 255) >> 2; cc[it] = lin & 3;
    }

    int4 xst[8], cst[4];
    #pragma unroll
    for (int it = 0; it < 8; it++)
        xst[it] = *(const int4*)&Xpl[(size_t)xq[it] * MP + (size_t)(m0 + xr_[it]) * P_SZ + xc[it] * 8];
    #pragma unroll
    for (int it = 0; it < 4; it++)
        cst[it] = *(const int4*)&Cpl[(size_t)cq[it] * PH + (size_t)(n0 + cr_[it]) * P_SZ + cc[it] * 8];

    for (int k0 = 0; k0 < P_SZ; k0 += 32) {
        __syncthreads();
        #pragma unroll
        for (int it = 0; it < 8; it++)
            *(int4*)&sS[xq[it] * 4096 + xr_[it] * 32 + xc[it] * 8] = xst[it];
        #pragma unroll
        for (int it = 0; it < 4; it++)
            *(int4*)&sS[16384 + cq[it] * 2048 + cr_[it] * 32 + cc[it] * 8] = cst[it];
        __syncthreads();
        if (k0 + 32 < P_SZ) {
            #pragma unroll
            for (int it = 0; it < 8; it++)
                xst[it] = *(const int4*)&Xpl[(size_t)xq[it] * MP + (size_t)(m0 + xr_[it]) * P_SZ + k0 + 32 + xc[it] * 8];
            #pragma unroll
            for (int it = 0; it < 4; it++)
                cst[it] = *(const int4*)&Cpl[(size_t)cq[it] * PH + (size_t)(n0 + cr_[it]) * P_SZ + k0 + 32 + cc[it] * 8];
        }

        bf16x8 xrh[4], xrl[4], xih[4], xil[4];
        #pragma unroll
        for (int mi = 0; mi < 4; mi++) {
            int off = (wm * 64 + mi * 16 + lr) * 32 + kg * 8;
            xrh[mi] = *(const bf16x8*)&sS[off];
            xrl[mi] = *(const bf16x8*)&sS[4096 + off];
            xih[mi] = *(const bf16x8*)&sS[8192 + off];
            xil[mi] = *(const bf16x8*)&sS[12288 + off];
        }
        bf16x8 crh[2], crl[2], cih[2], cil[2];
        #pragma unroll
        for (int nj = 0; nj < 2; nj++) {
            int off = (wn * 32 + nj * 16 + lr) * 32 + kg * 8;
            crh[nj] = *(const bf16x8*)&sS[16384 + off];
            crl[nj] = *(const bf16x8*)&sS[16384 + 2048 + off];
            cih[nj] = *(const bf16x8*)&sS[16384 + 4096 + off];
            cil[nj] = *(const bf16x8*)&sS[16384 + 6144 + off];
        }
        #pragma unroll
        for (int mi = 0; mi < 4; mi++)
            #pragma unroll
            for (int nj = 0; nj < 2; nj++) {
                acc[mi][nj] = __builtin_amdgcn_mfma_f32_16x16x32_bf16(xrh[mi], crh[nj], acc[mi][nj], 0, 0, 0);
                acc[mi][nj] = __builtin_amdgcn_mfma_f32_16x16x32_bf16(xrh[mi], crl[nj], acc[mi][nj], 0, 0, 0);
                acc[mi][nj] = __builtin_amdgcn_mfma_f32_16x16x32_bf16(xrl[mi], crh[nj], acc[mi][nj], 0, 0, 0);
                acc[mi][nj] = __builtin_amdgcn_mfma_f32_16x16x32_bf16(xih[mi], cih[nj], acc[mi][nj], 0, 0, 0);
                acc[mi][nj] = __builtin_amdgcn_mfma_f32_16x16x32_bf16(xih[mi], cil[nj], acc[mi][nj], 0, 0, 0);
                acc[mi][nj] = __builtin_amdgcn_mfma_f32_16x16x32_bf16(xil[mi], cih[nj], acc[mi][nj], 0, 0, 0);
            }
    }
    #pragma unroll
    for (int mi = 0; mi < 4; mi++)
        #pragma unroll
        for (int nj = 0; nj < 2; nj++)
            #pragma unroll
            for (int r = 0; r < 4; r++) {
                int m = m0 + wm * 64 + mi * 16 + kg * 4 + r;
                int h = n0 + wn * 32 + nj * 16 + lr;
                Y[(size_t)m * H_SZ + h] = 2.0f * acc[mi][nj][r];
            }
}

extern "C" void kernel_launch(void* const* d_in, const int* in_sizes, int n_in,
                              void* d_out, int out_size, void* d_ws, size_t ws_size,
                              hipStream_t stream) {
    const float* lam_re   = (const float*)d_in[0];
    const float* lam_im   = (const float*)d_in[1];
    const float* Bre      = (const float*)d_in[2];
    const float* Bim      = (const float*)d_in[3];
    const float* Cre      = (const float*)d_in[4];
    const float* Cim      = (const float*)d_in[5];
    const float* log_step = (const float*)d_in[6];
    const float* U        = (const float*)d_in[7];
    float* Y = (float*)d_out;

    char* ws = (char*)d_ws;
    unsigned short* Xpl = (unsigned short*)ws;                  // 4 planes M*P = 134.2 MB
    ws += (size_t)4 * MP * sizeof(unsigned short);
    unsigned short* Wpl = (unsigned short*)ws;                  // 2 MB
    ws += (size_t)4 * PH * sizeof(unsigned short);
    unsigned short* Cpl = (unsigned short*)ws;                  // 2 MB
    ws += (size_t)4 * PH * sizeof(unsigned short);
    float2* Lbar = (float2*)ws;  ws += P_SZ * sizeof(float2);
    float2* AS   = (float2*)ws;  ws += P_SZ * sizeof(float2);
    float2* scale = (float2*)ws; ws += P_SZ * sizeof(float2);
    float2* carries = (float2*)ws;                              // 1 MB
    ws += (size_t)B_SZ * NCH * P_SZ * sizeof(float2);
    float2* Ppow = (float2*)ws;                                 // 512 KB

    precompute_k<<<dim3((P_SZ + 255) / 256), dim3(256), 0, stream>>>(
        lam_re, lam_im, log_step, Lbar, AS, scale);
    ppow_k<<<dim3((CHUNK * P_SZ) / 256), dim3(256), 0, stream>>>(Lbar, Ppow);
    bbar_k<<<dim3(PH / 256), dim3(256), 0, stream>>>(Bre, Bim, scale, Wpl);
    csplit_k<<<dim3(PH / 256), dim3(256), 0, stream>>>(Cre, Cim, Cpl);
    gemm1_k<<<dim3((M_SZ / 128) * (P_SZ / 64)), dim3(256), 0, stream>>>(U, Wpl, Lbar, Xpl, carries);
    scanB_k<<<dim3((B_SZ * P_SZ) / 256), dim3(256), 0, stream>>>(carries, AS);
    fixup_k<<<dim3((M_SZ * P_SZ / 4) / 256), dim3(256), 0, stream>>>(Xpl, Ppow, carries);
    gemm2_k<<<dim3((M_SZ / 128) * (H_SZ / 64)), dim3(256), 0, stream>>>(Xpl, Cpl, Y);
}